// Round 3
// baseline (319.154 us; speedup 1.0000x reference)
//
#include <hip/hip_runtime.h>
#include <cmath>

#define N_NODES 4096
#define FDIM    256
#define CDIM    40
#define NEDGE   131072
#define CAP     256                  // ELL row capacity (row nnz ~Poisson(64))
#define HBITS   19
#define HSIZE   (1 << HBITS)         // 512K hash slots, load <= 0.25
#define TWO_PI_F 6.28318530717958647692f

typedef __bf16 bf16;
typedef __bf16 bf16x2 __attribute__((ext_vector_type(2)));
typedef __bf16 bf16x4 __attribute__((ext_vector_type(4)));
typedef __bf16 bf16x8 __attribute__((ext_vector_type(8)));
typedef float  f32x2  __attribute__((ext_vector_type(2)));
typedef float  f32x4  __attribute__((ext_vector_type(4)));

static constexpr size_t NF = (size_t)N_NODES * FDIM;      // 1,048,576

struct __align__(16) Entry { float lr, li; int col, pad; };

// async global->LDS, 16B per lane, dest = ldsBase + lane*16
__device__ __forceinline__ void gld_lds16(const bf16* g, bf16* s) {
    __builtin_amdgcn_global_load_lds(
        (const __attribute__((address_space(1))) void*)g,
        (__attribute__((address_space(3))) void*)s,
        16, 0, 0);
}

__device__ __forceinline__ unsigned cell_hash(unsigned cell) {
    return (cell * 2654435761u) >> (32 - HBITS);
}

// ---------------------------------------------------------------------------
// 1. Hash-insert edges (duplicate weights summed) + raw row/col degree sums.
// ---------------------------------------------------------------------------
__global__ void hash_insert(const int* __restrict__ edges,
                            const float* __restrict__ ew,
                            int* __restrict__ hkey, float* __restrict__ hval,
                            float* __restrict__ rowsum, float* __restrict__ colsum) {
    int e = blockIdx.x * blockDim.x + threadIdx.x;
    if (e >= NEDGE) return;
    int r = edges[e], c = edges[NEDGE + e];
    float wv = ew[e];
    atomicAdd(rowsum + r, wv);
    atomicAdd(colsum + c, wv);
    unsigned cell = (unsigned)r * N_NODES + c;      // < 2^24
    unsigned h = cell_hash(cell);
    for (;;) {
        int old = atomicCAS(hkey + h, 0, (int)(cell + 1));
        if (old == 0 || old == (int)(cell + 1)) { atomicAdd(hval + h, wv); break; }
        h = (h + 1) & (HSIZE - 1);
    }
}

// ---------------------------------------------------------------------------
// 2. Hash -> ELL, dinv inlined from rowsum/colsum.
// ---------------------------------------------------------------------------
__global__ __launch_bounds__(256) void hash_to_ell(
    const int* __restrict__ hkey, const float* __restrict__ hval,
    const float* __restrict__ rowsum, const float* __restrict__ colsum,
    const float* __restrict__ qptr,
    int* __restrict__ cnt, Entry* __restrict__ ent) {
    int h = blockIdx.x * 256 + threadIdx.x;
    int k = hkey[h];
    if (k == 0) return;
    unsigned cell = (unsigned)(k - 1);
    int i = cell >> 12, j = cell & 4095;
    float a = hval[h];
    float b = 0.f;
    bool mirror = false;
    if (i == j) { b = a; mirror = true; }
    else {
        unsigned mcell = (unsigned)j * N_NODES + i;
        unsigned hh = cell_hash(mcell);
        for (;;) {
            int kk = hkey[hh];
            if (kk == (int)(mcell + 1)) { b = hval[hh]; mirror = true; break; }
            if (kk == 0) break;
            hh = (hh + 1) & (HSIZE - 1);
        }
    }
    float di = 0.5f * (rowsum[i] + colsum[i]); if (di == 0.f) di = 1.f;
    float dj = 0.5f * (rowsum[j] + colsum[j]); if (dj == 0.f) dj = 1.f;
    float an = 0.5f * (a + b) / sqrtf(di * dj);
    float s, c;
    sincosf(TWO_PI_F * qptr[0] * (a - b), &s, &c);
    int pos = atomicAdd(cnt + i, 1);
    if (pos < CAP) {
        Entry en; en.lr = -an * c; en.li = an * s; en.col = j; en.pad = 0;
        ent[(size_t)i * CAP + pos] = en;
    }
    if (!mirror) {   // emit conjugate cell (j,i)
        int pos2 = atomicAdd(cnt + j, 1);
        if (pos2 < CAP) {
            Entry en; en.lr = -an * c; en.li = -an * s; en.col = i; en.pad = 0;
            ent[(size_t)j * CAP + pos2] = en;
        }
    }
}

// ---------------------------------------------------------------------------
// 3. Cast X -> planar bf16 (wapply input) + interleaved bf16 (spmm input)
// ---------------------------------------------------------------------------
__global__ __launch_bounds__(256) void cast_in2(const float* __restrict__ Xr,
                                                const float* __restrict__ Xi,
                                                bf16* __restrict__ Xr16,
                                                bf16* __restrict__ Xi16,
                                                bf16* __restrict__ XC) {
    int idx = blockIdx.x * 256 + threadIdx.x;     // n*256+f
    float vr = Xr[idx], vi = Xi[idx];
    Xr16[idx] = (bf16)vr; Xi16[idx] = (bf16)vi;
    bf16x2 p; p[0] = (bf16)vr; p[1] = (bf16)vi;
    ((bf16x2*)XC)[idx] = p;
}

// ---------------------------------------------------------------------------
// 4. Fused weight casts.
// ---------------------------------------------------------------------------
#define NWT (256 * 768)
__global__ __launch_bounds__(256) void cast_weights(
    const float* __restrict__ W1, const float* __restrict__ W2,
    const float* __restrict__ Wc,
    bf16* __restrict__ W1t, bf16* __restrict__ W2t, bf16* __restrict__ Wcb) {
    int idx = blockIdx.x * 256 + threadIdx.x;
    if (idx < 2 * NWT) {
        const float* W = (idx < NWT) ? W1 : W2;
        bf16* Wt = (idx < NWT) ? W1t : W2t;
        int id = (idx < NWT) ? idx : idx - NWT;
        int nout = id / 768, kk = id - nout * 768;
        int o = kk >> 8, k = kk & 255;
        Wt[id] = (bf16)W[((size_t)o * 256 + k) * 256 + nout];
    } else {
        int id = idx - 2 * NWT;
        if (id < 48 * 512) {
            int row = id >> 9, k = id & 511;
            Wcb[id] = (row < CDIM) ? (bf16)Wc[row * 512 + k] : (bf16)0.f;
        }
    }
}

// ---------------------------------------------------------------------------
// 5. Sparse complex SpMM (ELL), v5: feature-panel split. Grid = 8192 blocks;
//    bid 0..4095 = panel 0 (complex feats 0..127), 4096..8191 = panel 1.
//    Panel gather target = 2 MB (< 4 MB per-XCD L2 even with Entry stream +
//    store traffic co-resident). Dispatch order gives temporal separation of
//    the two panels (performance heuristic only; correctness independent).
//    Each lane gathers bf16x4 (2 complex feats); 4 entries in flight.
// ---------------------------------------------------------------------------
__global__ __launch_bounds__(256) void spmm_k(
    const int* __restrict__ cnt, const Entry* __restrict__ ent,
    const bf16* __restrict__ XC,
    const bf16* __restrict__ C0C,
    float alpha, float beta,
    bf16* __restrict__ Zr, bf16* __restrict__ Zi, bf16* __restrict__ ZC)
{
    __shared__ f32x2 redR[3][64];
    __shared__ f32x2 redI[3][64];

    const int wave = threadIdx.x >> 6, lane = threadIdx.x & 63;
    const int bid = blockIdx.x;
    const int row   = bid & (N_NODES - 1);
    const int panel = bid >> 12;                    // 0 or 1
    int n1 = cnt[row]; if (n1 > CAP) n1 = CAP;
    const Entry* erow = ent + (size_t)row * CAP;

    // gather offset of this lane within a node row (interleaved layout):
    // node*512 + panel*256 + lane*4  (elems), 4 bf16 = 2 complex features
    const int goff = panel * 256 + lane * 4;

    float ar[2] = {}, ai[2] = {};
    int e = wave;
    // 4 independent XC gathers in flight (entries e, e+4, e+8, e+12)
    for (; e + 12 < n1; e += 16) {
        Entry e0 = erow[e];
        Entry e1 = erow[e + 4];
        Entry e2 = erow[e + 8];
        Entry e3 = erow[e + 12];
        bf16x4 x0 = *(const bf16x4*)&XC[(size_t)(e0.col & 4095) * 512 + goff];
        bf16x4 x1 = *(const bf16x4*)&XC[(size_t)(e1.col & 4095) * 512 + goff];
        bf16x4 x2 = *(const bf16x4*)&XC[(size_t)(e2.col & 4095) * 512 + goff];
        bf16x4 x3 = *(const bf16x4*)&XC[(size_t)(e3.col & 4095) * 512 + goff];
        #pragma unroll
        for (int c = 0; c < 2; ++c) {
            float xr, xi;
            xr = (float)x0[2 * c]; xi = (float)x0[2 * c + 1];
            ar[c] += e0.lr * xr - e0.li * xi;  ai[c] += e0.lr * xi + e0.li * xr;
            xr = (float)x1[2 * c]; xi = (float)x1[2 * c + 1];
            ar[c] += e1.lr * xr - e1.li * xi;  ai[c] += e1.lr * xi + e1.li * xr;
            xr = (float)x2[2 * c]; xi = (float)x2[2 * c + 1];
            ar[c] += e2.lr * xr - e2.li * xi;  ai[c] += e2.lr * xi + e2.li * xr;
            xr = (float)x3[2 * c]; xi = (float)x3[2 * c + 1];
            ar[c] += e3.lr * xr - e3.li * xi;  ai[c] += e3.lr * xi + e3.li * xr;
        }
    }
    for (; e < n1; e += 4) {
        Entry e0 = erow[e];
        bf16x4 x0 = *(const bf16x4*)&XC[(size_t)(e0.col & 4095) * 512 + goff];
        #pragma unroll
        for (int c = 0; c < 2; ++c) {
            float xr0 = (float)x0[2 * c], xi0 = (float)x0[2 * c + 1];
            ar[c] += e0.lr * xr0 - e0.li * xi0;
            ai[c] += e0.lr * xi0 + e0.li * xr0;
        }
    }

    if (wave != 0) {
        f32x2 r, i;
        #pragma unroll
        for (int c = 0; c < 2; ++c) { r[c] = ar[c]; i[c] = ai[c]; }
        redR[wave - 1][lane] = r;
        redI[wave - 1][lane] = i;
    }
    __syncthreads();
    if (wave != 0) return;

    #pragma unroll
    for (int w = 0; w < 3; ++w) {
        f32x2 r = redR[w][lane], i = redI[w][lane];
        #pragma unroll
        for (int c = 0; c < 2; ++c) { ar[c] += r[c]; ai[c] += i[c]; }
    }

    float vr[2], vi[2];
    if (beta != 0.f) {
        bf16x4 c0 = *(const bf16x4*)&C0C[(size_t)row * 512 + goff];
        #pragma unroll
        for (int c = 0; c < 2; ++c) {
            vr[c] = alpha * ar[c] + beta * (float)c0[2 * c];
            vi[c] = alpha * ai[c] + beta * (float)c0[2 * c + 1];
        }
    } else {
        #pragma unroll
        for (int c = 0; c < 2; ++c) { vr[c] = alpha * ar[c]; vi[c] = alpha * ai[c]; }
    }
    size_t base = (size_t)row * FDIM + panel * 128 + lane * 2;
    bf16x2 pr, pi;
    #pragma unroll
    for (int c = 0; c < 2; ++c) { pr[c] = (bf16)vr[c]; pi[c] = (bf16)vi[c]; }
    *(bf16x2*)&Zr[base] = pr;
    *(bf16x2*)&Zi[base] = pi;
    if (ZC) {
        bf16x4 o;
        #pragma unroll
        for (int c = 0; c < 2; ++c) { o[2 * c] = pr[c]; o[2 * c + 1] = pi[c]; }
        *(bf16x4*)&ZC[(size_t)row * 512 + goff] = o;
    }
}

// ---------------------------------------------------------------------------
// 6. wapply via MFMA (dead f32 outputs removed; otherwise byte-identical).
// ---------------------------------------------------------------------------
__global__ __launch_bounds__(256) void wapply_mfma(
    const bf16* __restrict__ Z0r, const bf16* __restrict__ Z0i,
    const bf16* __restrict__ Z1r, const bf16* __restrict__ Z1i,
    const bf16* __restrict__ Z2r, const bf16* __restrict__ Z2i,
    const bf16* __restrict__ Wt,      // [256][768]
    const float* __restrict__ bias,   // [256]
    bf16* __restrict__ O16r_r, bf16* __restrict__ O16r_i,
    bf16* __restrict__ OC)
{
    __shared__ __align__(16) bf16 sZr[64 * 32];
    __shared__ __align__(16) bf16 sZi[64 * 32];
    __shared__ __align__(16) bf16 sW [64 * 32];

    const int tid  = threadIdx.x;
    const int wave = tid >> 6;
    const int lane = tid & 63;
    const int rowBase = blockIdx.y * 64;
    const int colBase = blockIdx.x * 64;

    const int srow = lane >> 2;
    const int skc  = (lane & 3) * 8;

    f32x4 accSr[2][2] = {}, accSi[2][2] = {};
    const int wm = wave & 1, wn = wave >> 1;
    const int fr = lane & 15;
    const int fk = (lane >> 4) * 8;

    for (int kb = 0; kb < 3 * FDIM; kb += 32) {
        int order = kb >> 8;
        int kloc  = kb & 255;
        if (wave == 0 || wave == 1) {
            const bf16* z;
            if (wave == 0) z = (order == 0) ? Z0r : (order == 1) ? Z1r : Z2r;
            else           z = (order == 0) ? Z0i : (order == 1) ? Z1i : Z2i;
            bf16* s = (wave == 0) ? sZr : sZi;
            const bf16* g = z + (size_t)(rowBase + srow) * FDIM + kloc + skc;
            #pragma unroll
            for (int t = 0; t < 4; ++t)
                gld_lds16(g + (size_t)t * 16 * FDIM, s + t * 512);
        } else if (wave == 2) {
            const bf16* g = Wt + (size_t)(colBase + srow) * 768 + kb + skc;
            #pragma unroll
            for (int t = 0; t < 4; ++t)
                gld_lds16(g + (size_t)t * 16 * 768, sW + t * 512);
        }
        __syncthreads();

        bf16x8 zr[2], zi[2], wv[2];
        #pragma unroll
        for (int m = 0; m < 2; ++m) {
            int r = wm * 32 + m * 16 + fr;
            zr[m] = *(const bf16x8*)&sZr[r * 32 + fk];
            zi[m] = *(const bf16x8*)&sZi[r * 32 + fk];
        }
        #pragma unroll
        for (int n = 0; n < 2; ++n) {
            int c = wn * 32 + n * 16 + fr;
            wv[n] = *(const bf16x8*)&sW[c * 32 + fk];
        }
        #pragma unroll
        for (int m = 0; m < 2; ++m)
            #pragma unroll
            for (int n = 0; n < 2; ++n) {
                accSr[m][n] = __builtin_amdgcn_mfma_f32_16x16x32_bf16(zr[m], wv[n], accSr[m][n], 0, 0, 0);
                accSi[m][n] = __builtin_amdgcn_mfma_f32_16x16x32_bf16(zi[m], wv[n], accSi[m][n], 0, 0, 0);
            }
        __syncthreads();
    }

    #pragma unroll
    for (int m = 0; m < 2; ++m)
        #pragma unroll
        for (int n = 0; n < 2; ++n) {
            int row0 = rowBase + wm * 32 + m * 16 + (lane >> 4) * 4;
            int col  = colBase + wn * 32 + n * 16 + (lane & 15);
            float bv = bias[col];
            #pragma unroll
            for (int r = 0; r < 4; ++r) {
                float vr = bv - accSi[m][n][r];
                float vi = bv + accSr[m][n][r];
                int row = row0 + r;
                size_t idx = (size_t)row * FDIM + col;
                if (O16r_r) {
                    O16r_r[idx] = (bf16)vr; O16r_i[idx] = (bf16)vi;
                }
                if (OC) {
                    bf16x2 p; p[0] = (bf16)vr; p[1] = (bf16)vi;
                    ((bf16x2*)OC)[idx] = p;
                }
            }
        }
}

// ---------------------------------------------------------------------------
// 7. Head via MFMA + fused log_softmax (unchanged).
// ---------------------------------------------------------------------------
__global__ __launch_bounds__(256) void head_mfma(
    const bf16* __restrict__ Yrb,
    const bf16* __restrict__ Yib,
    const bf16* __restrict__ Wcb,
    const float* __restrict__ bc,
    float* __restrict__ out)          // [4096][40]
{
    __shared__ __align__(16) bf16 sY[64][72];
    __shared__ __align__(16) bf16 sW[48][72];
    __shared__ float sS[64][52];

    const int tid  = threadIdx.x;
    const int wave = tid >> 6;
    const int lane = tid & 63;
    const int r0 = blockIdx.x * 64;

    f32x4 acc[3] = {};

    for (int kb = 0; kb < 512; kb += 64) {
        const bf16* src = (kb < 256) ? Yrb : Yib;
        const int koff = kb & 255;
        #pragma unroll
        for (int e = 0; e < 2; ++e) {
            int idx = tid + e * 256;             // 0..511
            int rr = idx >> 3, kk = (idx & 7) * 8;
            *(bf16x8*)&sY[rr][kk] =
                *(const bf16x8*)&src[(size_t)(r0 + rr) * FDIM + koff + kk];
        }
        #pragma unroll
        for (int e = 0; e < 2; ++e) {
            int idx = tid + e * 256;             // need 0..383
            if (idx < 384) {
                int rr = idx >> 3, kk = (idx & 7) * 8;
                *(bf16x8*)&sW[rr][kk] =
                    *(const bf16x8*)&Wcb[(size_t)rr * 512 + kb + kk];
            }
        }
        __syncthreads();
        #pragma unroll
        for (int ks = 0; ks < 2; ++ks) {
            bf16x8 a = *(const bf16x8*)&sY[wave * 16 + (lane & 15)][ks * 32 + (lane >> 4) * 8];
            #pragma unroll
            for (int n = 0; n < 3; ++n) {
                bf16x8 b = *(const bf16x8*)&sW[n * 16 + (lane & 15)][ks * 32 + (lane >> 4) * 8];
                acc[n] = __builtin_amdgcn_mfma_f32_16x16x32_bf16(a, b, acc[n], 0, 0, 0);
            }
        }
        __syncthreads();
    }

    #pragma unroll
    for (int n = 0; n < 3; ++n) {
        int col = n * 16 + (lane & 15);
        int rloc = wave * 16 + (lane >> 4) * 4;
        #pragma unroll
        for (int r = 0; r < 4; ++r)
            sS[rloc + r][col] = acc[n][r];
    }
    __syncthreads();

    if (tid < 64) {
        float mx = -INFINITY;
        #pragma unroll 8
        for (int c = 0; c < CDIM; ++c) {
            float lv = sS[tid][c] + bc[c];
            sS[tid][c] = lv;
            mx = fmaxf(mx, lv);
        }
        float se = 0.f;
        #pragma unroll 8
        for (int c = 0; c < CDIM; ++c) se += expf(sS[tid][c] - mx);
        float lse = mx + logf(se);
        #pragma unroll 8
        for (int c = 0; c < CDIM; ++c)
            out[(size_t)(r0 + tid) * CDIM + c] = sS[tid][c] - lse;
    }
}

// ---------------------------------------------------------------------------
// Launcher
// ---------------------------------------------------------------------------
extern "C" void kernel_launch(void* const* d_in, const int* in_sizes, int n_in,
                              void* d_out, int out_size, void* d_ws, size_t ws_size,
                              hipStream_t stream) {
    const float* real = (const float*)d_in[0];
    const float* imag = (const float*)d_in[1];
    const int*   edges = (const int*)d_in[2];
    const float* q    = (const float*)d_in[3];
    const float* ew   = (const float*)d_in[4];
    const float* W1   = (const float*)d_in[5];
    const float* b1   = (const float*)d_in[6];
    const float* W2   = (const float*)d_in[7];
    const float* b2   = (const float*)d_in[8];
    const float* Wc   = (const float*)d_in[9];
    const float* bc   = (const float*)d_in[10];
    float* out = (float*)d_out;

    // ---- workspace carve-up ----
    char* w = (char*)d_ws;
    int*      hkey   = (int*)w;   w += (size_t)HSIZE * 4;       // 2 MB
    float*    hval   = (float*)w; w += (size_t)HSIZE * 4;       // 2 MB
    int*      cnt    = (int*)w;   w += N_NODES * 4;
    float*    rowsum = (float*)w; w += N_NODES * 4;
    float*    colsum = (float*)w; w += N_NODES * 4;
    size_t zero_bytes = (size_t)((char*)w - (char*)d_ws);
    // Non-zeroed:
    Entry* ent  = (Entry*)w; w += (size_t)N_NODES * CAP * 16;   // 16 MB
    bf16* Xr16 = (bf16*)w; w += NF * 2;
    bf16* Xi16 = (bf16*)w; w += NF * 2;
    bf16* XC   = (bf16*)w; w += NF * 4;                         // interleaved
    bf16* Z1r  = (bf16*)w; w += NF * 2;
    bf16* Z1i  = (bf16*)w; w += NF * 2;
    bf16* Z1C  = (bf16*)w; w += NF * 4;
    bf16* Z2r  = (bf16*)w; w += NF * 2;
    bf16* Z2i  = (bf16*)w; w += NF * 2;
    bf16* Y1rb = (bf16*)w; w += NF * 2;
    bf16* Y1ib = (bf16*)w; w += NF * 2;
    bf16* Y1C  = (bf16*)w; w += NF * 4;
    bf16* Y2rb = (bf16*)w; w += NF * 2;
    bf16* Y2ib = (bf16*)w; w += NF * 2;
    bf16* W1t  = (bf16*)w; w += 256 * 768 * 2;
    bf16* W2t  = (bf16*)w; w += 256 * 768 * 2;
    bf16* Wcb  = (bf16*)w; w += 48 * 512 * 2;

    hipMemsetAsync(d_ws, 0, zero_bytes, stream);

    // ---- build sparse L (hash -> ELL) ----
    hash_insert<<<(NEDGE + 255) / 256, 256, 0, stream>>>(edges, ew, hkey, hval,
                                                         rowsum, colsum);
    hash_to_ell<<<HSIZE / 256, 256, 0, stream>>>(hkey, hval, rowsum, colsum,
                                                 q, cnt, ent);

    // ---- casts ----
    cast_in2<<<NF / 256, 256, 0, stream>>>(real, imag, Xr16, Xi16, XC);
    cast_weights<<<(2 * NWT + 48 * 512 + 255) / 256, 256, 0, stream>>>(
        W1, W2, Wc, W1t, W2t, Wcb);

    dim3 gW(FDIM / 64, N_NODES / 64);   // (4, 64)
    const int gS = 2 * N_NODES;         // 2 feature panels x 4096 rows

    // ---- Layer 1 ----
    spmm_k<<<gS, 256, 0, stream>>>(cnt, ent, XC, nullptr,
                                   1.f, 0.f, Z1r, Z1i, Z1C);
    spmm_k<<<gS, 256, 0, stream>>>(cnt, ent, Z1C, XC,
                                   2.f, -1.f, Z2r, Z2i, nullptr);
    wapply_mfma<<<gW, 256, 0, stream>>>(Xr16, Xi16, Z1r, Z1i, Z2r, Z2i,
                                        W1t, b1,
                                        Y1rb, Y1ib,
                                        Y1C);

    // ---- Layer 2 ----
    spmm_k<<<gS, 256, 0, stream>>>(cnt, ent, Y1C, nullptr,
                                   1.f, 0.f, Z1r, Z1i, Z1C);
    spmm_k<<<gS, 256, 0, stream>>>(cnt, ent, Z1C, Y1C,
                                   2.f, -1.f, Z2r, Z2i, nullptr);
    wapply_mfma<<<gW, 256, 0, stream>>>(Y1rb, Y1ib, Z1r, Z1i, Z2r, Z2i,
                                        W2t, b2,
                                        Y2rb, Y2ib,
                                        nullptr);

    // ---- Head ----
    head_mfma<<<64, 256, 0, stream>>>(Y2rb, Y2ib, Wcb, bc, out);
}

// Round 4
// 314.879 us; speedup vs baseline: 1.0136x; 1.0136x over previous
//
#include <hip/hip_runtime.h>
#include <cmath>

#define N_NODES 4096
#define FDIM    256
#define CDIM    40
#define NEDGE   131072
#define CAP     256                  // ELL row capacity (row nnz ~Poisson(64))
#define HBITS   20
#define HSIZE   (1 << HBITS)         // 1M hash slots, load <= 0.125
#define TWO_PI_F 6.28318530717958647692f

typedef __bf16 bf16;
typedef __bf16 bf16x2 __attribute__((ext_vector_type(2)));
typedef __bf16 bf16x4 __attribute__((ext_vector_type(4)));
typedef __bf16 bf16x8 __attribute__((ext_vector_type(8)));
typedef float  f32x4  __attribute__((ext_vector_type(4)));

static constexpr size_t NF = (size_t)N_NODES * FDIM;      // 1,048,576

struct __align__(16) Entry { float lr, li; int col, pad; };

// wave-uniform value -> SGPR (entries are read at wave-uniform indices)
__device__ __forceinline__ float rfl_f(float x) {
    return __uint_as_float(__builtin_amdgcn_readfirstlane(__float_as_uint(x)));
}
__device__ __forceinline__ int rfl_i(int x) {
    return __builtin_amdgcn_readfirstlane(x);
}

// async global->LDS, 16B per lane, dest = ldsBase + lane*16
__device__ __forceinline__ void gld_lds16(const bf16* g, bf16* s) {
    __builtin_amdgcn_global_load_lds(
        (const __attribute__((address_space(1))) void*)g,
        (__attribute__((address_space(3))) void*)s,
        16, 0, 0);
}

__device__ __forceinline__ unsigned cell_hash(unsigned cell) {
    return (cell * 2654435761u) >> (32 - HBITS);
}

// ---------------------------------------------------------------------------
// 1. Hash-insert edges (duplicate weights summed) + raw row/col degree sums.
// ---------------------------------------------------------------------------
__global__ void hash_insert(const int* __restrict__ edges,
                            const float* __restrict__ ew,
                            int* __restrict__ hkey, float* __restrict__ hval,
                            float* __restrict__ rowsum, float* __restrict__ colsum) {
    int e = blockIdx.x * blockDim.x + threadIdx.x;
    if (e >= NEDGE) return;
    int r = edges[e], c = edges[NEDGE + e];
    float wv = ew[e];
    atomicAdd(rowsum + r, wv);
    atomicAdd(colsum + c, wv);
    unsigned cell = (unsigned)r * N_NODES + c;      // < 2^24
    unsigned h = cell_hash(cell);
    for (;;) {
        int old = atomicCAS(hkey + h, 0, (int)(cell + 1));
        if (old == 0 || old == (int)(cell + 1)) { atomicAdd(hval + h, wv); break; }
        h = (h + 1) & (HSIZE - 1);
    }
}

// ---------------------------------------------------------------------------
// 2. Hash -> ELL, dinv inlined from rowsum/colsum.
// ---------------------------------------------------------------------------
__global__ __launch_bounds__(256) void hash_to_ell(
    const int* __restrict__ hkey, const float* __restrict__ hval,
    const float* __restrict__ rowsum, const float* __restrict__ colsum,
    const float* __restrict__ qptr,
    int* __restrict__ cnt, Entry* __restrict__ ent) {
    int h = blockIdx.x * 256 + threadIdx.x;
    int k = hkey[h];
    if (k == 0) return;
    unsigned cell = (unsigned)(k - 1);
    int i = cell >> 12, j = cell & 4095;
    float a = hval[h];
    float b = 0.f;
    bool mirror = false;
    if (i == j) { b = a; mirror = true; }
    else {
        unsigned mcell = (unsigned)j * N_NODES + i;
        unsigned hh = cell_hash(mcell);
        for (;;) {
            int kk = hkey[hh];
            if (kk == (int)(mcell + 1)) { b = hval[hh]; mirror = true; break; }
            if (kk == 0) break;
            hh = (hh + 1) & (HSIZE - 1);
        }
    }
    float di = 0.5f * (rowsum[i] + colsum[i]); if (di == 0.f) di = 1.f;
    float dj = 0.5f * (rowsum[j] + colsum[j]); if (dj == 0.f) dj = 1.f;
    float an = 0.5f * (a + b) / sqrtf(di * dj);
    float s, c;
    sincosf(TWO_PI_F * qptr[0] * (a - b), &s, &c);
    int pos = atomicAdd(cnt + i, 1);
    if (pos < CAP) {
        Entry en; en.lr = -an * c; en.li = an * s; en.col = j; en.pad = 0;
        ent[(size_t)i * CAP + pos] = en;
    }
    if (!mirror) {   // emit conjugate cell (j,i)
        int pos2 = atomicAdd(cnt + j, 1);
        if (pos2 < CAP) {
            Entry en; en.lr = -an * c; en.li = -an * s; en.col = i; en.pad = 0;
            ent[(size_t)j * CAP + pos2] = en;
        }
    }
}

// ---------------------------------------------------------------------------
// 3. Cast X -> planar bf16 (wapply input) + interleaved bf16 (spmm input)
// ---------------------------------------------------------------------------
__global__ __launch_bounds__(256) void cast_in2(const float* __restrict__ Xr,
                                                const float* __restrict__ Xi,
                                                bf16* __restrict__ Xr16,
                                                bf16* __restrict__ Xi16,
                                                bf16* __restrict__ XC) {
    int idx = blockIdx.x * 256 + threadIdx.x;     // n*256+f
    float vr = Xr[idx], vi = Xi[idx];
    Xr16[idx] = (bf16)vr; Xi16[idx] = (bf16)vi;
    bf16x2 p; p[0] = (bf16)vr; p[1] = (bf16)vi;
    ((bf16x2*)XC)[idx] = p;
}

// ---------------------------------------------------------------------------
// 4. Fused weight casts.
// ---------------------------------------------------------------------------
#define NWT (256 * 768)
__global__ __launch_bounds__(256) void cast_weights(
    const float* __restrict__ W1, const float* __restrict__ W2,
    const float* __restrict__ Wc,
    bf16* __restrict__ W1t, bf16* __restrict__ W2t, bf16* __restrict__ Wcb) {
    int idx = blockIdx.x * 256 + threadIdx.x;
    if (idx < 2 * NWT) {
        const float* W = (idx < NWT) ? W1 : W2;
        bf16* Wt = (idx < NWT) ? W1t : W2t;
        int id = (idx < NWT) ? idx : idx - NWT;
        int nout = id / 768, kk = id - nout * 768;
        int o = kk >> 8, k = kk & 255;
        Wt[id] = (bf16)W[((size_t)o * 256 + k) * 256 + nout];
    } else {
        int id = idx - 2 * NWT;
        if (id < 48 * 512) {
            int row = id >> 9, k = id & 511;
            Wcb[id] = (row < CDIM) ? (bf16)Wc[row * 512 + k] : (bf16)0.f;
        }
    }
}

// ---------------------------------------------------------------------------
// 5. Sparse complex SpMM (ELL), v6: one block (4 waves) per row, entries
//    wave-strided, 8 outstanding XC gathers per wave (was 4), Entry fields
//    scalarized to SGPRs via readfirstlane (wave-uniform by construction).
// ---------------------------------------------------------------------------
__global__ __launch_bounds__(256) void spmm_k(
    const int* __restrict__ cnt, const Entry* __restrict__ ent,
    const bf16* __restrict__ XC,
    const bf16* __restrict__ C0C,
    float alpha, float beta,
    bf16* __restrict__ Zr, bf16* __restrict__ Zi, bf16* __restrict__ ZC)
{
    __shared__ f32x4 redR[3][64];
    __shared__ f32x4 redI[3][64];

    const int wave = threadIdx.x >> 6, lane = threadIdx.x & 63;
    const int row = blockIdx.x;
    int n1 = cnt[row]; if (n1 > CAP) n1 = CAP;
    const Entry* erow = ent + (size_t)row * CAP;

    float ar[4] = {}, ai[4] = {};
    int e = wave;
    // 8 independent XC gathers in flight (entries e, e+4, ..., e+28)
    for (; e + 28 < n1; e += 32) {
        float slr[8], sli[8];
        const bf16* gp[8];
        #pragma unroll
        for (int u = 0; u < 8; ++u) {
            Entry eu = erow[e + 4 * u];
            slr[u] = rfl_f(eu.lr);
            sli[u] = rfl_f(eu.li);
            int sc = rfl_i(eu.col) & 4095;
            gp[u] = &XC[(size_t)sc * 512 + lane * 8];
        }
        bf16x8 xv[8];
        #pragma unroll
        for (int u = 0; u < 8; ++u)
            xv[u] = *(const bf16x8*)gp[u];
        #pragma unroll
        for (int u = 0; u < 8; ++u) {
            #pragma unroll
            for (int c = 0; c < 4; ++c) {
                float xr = (float)xv[u][2 * c], xi = (float)xv[u][2 * c + 1];
                ar[c] += slr[u] * xr - sli[u] * xi;
                ai[c] += slr[u] * xi + sli[u] * xr;
            }
        }
    }
    for (; e < n1; e += 4) {
        Entry e0 = erow[e];
        float lr0 = rfl_f(e0.lr), li0 = rfl_f(e0.li);
        int   c0  = rfl_i(e0.col) & 4095;
        bf16x8 x0 = *(const bf16x8*)&XC[(size_t)c0 * 512 + lane * 8];
        #pragma unroll
        for (int c = 0; c < 4; ++c) {
            float xr0 = (float)x0[2 * c], xi0 = (float)x0[2 * c + 1];
            ar[c] += lr0 * xr0 - li0 * xi0;
            ai[c] += lr0 * xi0 + li0 * xr0;
        }
    }

    if (wave != 0) {
        f32x4 r, i;
        #pragma unroll
        for (int c = 0; c < 4; ++c) { r[c] = ar[c]; i[c] = ai[c]; }
        redR[wave - 1][lane] = r;
        redI[wave - 1][lane] = i;
    }
    __syncthreads();
    if (wave != 0) return;

    #pragma unroll
    for (int w = 0; w < 3; ++w) {
        f32x4 r = redR[w][lane], i = redI[w][lane];
        #pragma unroll
        for (int c = 0; c < 4; ++c) { ar[c] += r[c]; ai[c] += i[c]; }
    }

    float vr[4], vi[4];
    if (beta != 0.f) {
        bf16x8 c0 = *(const bf16x8*)&C0C[(size_t)row * 512 + lane * 8];
        #pragma unroll
        for (int c = 0; c < 4; ++c) {
            vr[c] = alpha * ar[c] + beta * (float)c0[2 * c];
            vi[c] = alpha * ai[c] + beta * (float)c0[2 * c + 1];
        }
    } else {
        #pragma unroll
        for (int c = 0; c < 4; ++c) { vr[c] = alpha * ar[c]; vi[c] = alpha * ai[c]; }
    }
    size_t base = (size_t)row * FDIM + lane * 4;
    bf16x4 pr, pi;
    #pragma unroll
    for (int c = 0; c < 4; ++c) { pr[c] = (bf16)vr[c]; pi[c] = (bf16)vi[c]; }
    *(bf16x4*)&Zr[base] = pr;
    *(bf16x4*)&Zi[base] = pi;
    if (ZC) {
        bf16x8 o;
        #pragma unroll
        for (int c = 0; c < 4; ++c) { o[2 * c] = pr[c]; o[2 * c + 1] = pi[c]; }
        *(bf16x8*)&ZC[(size_t)row * 512 + lane * 8] = o;
    }
}

// ---------------------------------------------------------------------------
// 6. wapply via MFMA (dead f32 outputs removed; otherwise round-0 identical).
// ---------------------------------------------------------------------------
__global__ __launch_bounds__(256) void wapply_mfma(
    const bf16* __restrict__ Z0r, const bf16* __restrict__ Z0i,
    const bf16* __restrict__ Z1r, const bf16* __restrict__ Z1i,
    const bf16* __restrict__ Z2r, const bf16* __restrict__ Z2i,
    const bf16* __restrict__ Wt,      // [256][768]
    const float* __restrict__ bias,   // [256]
    bf16* __restrict__ O16r_r, bf16* __restrict__ O16r_i,
    bf16* __restrict__ OC)
{
    __shared__ __align__(16) bf16 sZr[64 * 32];
    __shared__ __align__(16) bf16 sZi[64 * 32];
    __shared__ __align__(16) bf16 sW [64 * 32];

    const int tid  = threadIdx.x;
    const int wave = tid >> 6;
    const int lane = tid & 63;
    const int rowBase = blockIdx.y * 64;
    const int colBase = blockIdx.x * 64;

    const int srow = lane >> 2;
    const int skc  = (lane & 3) * 8;

    f32x4 accSr[2][2] = {}, accSi[2][2] = {};
    const int wm = wave & 1, wn = wave >> 1;
    const int fr = lane & 15;
    const int fk = (lane >> 4) * 8;

    for (int kb = 0; kb < 3 * FDIM; kb += 32) {
        int order = kb >> 8;
        int kloc  = kb & 255;
        if (wave == 0 || wave == 1) {
            const bf16* z;
            if (wave == 0) z = (order == 0) ? Z0r : (order == 1) ? Z1r : Z2r;
            else           z = (order == 0) ? Z0i : (order == 1) ? Z1i : Z2i;
            bf16* s = (wave == 0) ? sZr : sZi;
            const bf16* g = z + (size_t)(rowBase + srow) * FDIM + kloc + skc;
            #pragma unroll
            for (int t = 0; t < 4; ++t)
                gld_lds16(g + (size_t)t * 16 * FDIM, s + t * 512);
        } else if (wave == 2) {
            const bf16* g = Wt + (size_t)(colBase + srow) * 768 + kb + skc;
            #pragma unroll
            for (int t = 0; t < 4; ++t)
                gld_lds16(g + (size_t)t * 16 * 768, sW + t * 512);
        }
        __syncthreads();

        bf16x8 zr[2], zi[2], wv[2];
        #pragma unroll
        for (int m = 0; m < 2; ++m) {
            int r = wm * 32 + m * 16 + fr;
            zr[m] = *(const bf16x8*)&sZr[r * 32 + fk];
            zi[m] = *(const bf16x8*)&sZi[r * 32 + fk];
        }
        #pragma unroll
        for (int n = 0; n < 2; ++n) {
            int c = wn * 32 + n * 16 + fr;
            wv[n] = *(const bf16x8*)&sW[c * 32 + fk];
        }
        #pragma unroll
        for (int m = 0; m < 2; ++m)
            #pragma unroll
            for (int n = 0; n < 2; ++n) {
                accSr[m][n] = __builtin_amdgcn_mfma_f32_16x16x32_bf16(zr[m], wv[n], accSr[m][n], 0, 0, 0);
                accSi[m][n] = __builtin_amdgcn_mfma_f32_16x16x32_bf16(zi[m], wv[n], accSi[m][n], 0, 0, 0);
            }
        __syncthreads();
    }

    #pragma unroll
    for (int m = 0; m < 2; ++m)
        #pragma unroll
        for (int n = 0; n < 2; ++n) {
            int row0 = rowBase + wm * 32 + m * 16 + (lane >> 4) * 4;
            int col  = colBase + wn * 32 + n * 16 + (lane & 15);
            float bv = bias[col];
            #pragma unroll
            for (int r = 0; r < 4; ++r) {
                float vr = bv - accSi[m][n][r];
                float vi = bv + accSr[m][n][r];
                int row = row0 + r;
                size_t idx = (size_t)row * FDIM + col;
                if (O16r_r) {
                    O16r_r[idx] = (bf16)vr; O16r_i[idx] = (bf16)vi;
                }
                if (OC) {
                    bf16x2 p; p[0] = (bf16)vr; p[1] = (bf16)vi;
                    ((bf16x2*)OC)[idx] = p;
                }
            }
        }
}

// ---------------------------------------------------------------------------
// 7. Head via MFMA + fused log_softmax (unchanged).
// ---------------------------------------------------------------------------
__global__ __launch_bounds__(256) void head_mfma(
    const bf16* __restrict__ Yrb,
    const bf16* __restrict__ Yib,
    const bf16* __restrict__ Wcb,
    const float* __restrict__ bc,
    float* __restrict__ out)          // [4096][40]
{
    __shared__ __align__(16) bf16 sY[64][72];
    __shared__ __align__(16) bf16 sW[48][72];
    __shared__ float sS[64][52];

    const int tid  = threadIdx.x;
    const int wave = tid >> 6;
    const int lane = tid & 63;
    const int r0 = blockIdx.x * 64;

    f32x4 acc[3] = {};

    for (int kb = 0; kb < 512; kb += 64) {
        const bf16* src = (kb < 256) ? Yrb : Yib;
        const int koff = kb & 255;
        #pragma unroll
        for (int e = 0; e < 2; ++e) {
            int idx = tid + e * 256;             // 0..511
            int rr = idx >> 3, kk = (idx & 7) * 8;
            *(bf16x8*)&sY[rr][kk] =
                *(const bf16x8*)&src[(size_t)(r0 + rr) * FDIM + koff + kk];
        }
        #pragma unroll
        for (int e = 0; e < 2; ++e) {
            int idx = tid + e * 256;             // need 0..383
            if (idx < 384) {
                int rr = idx >> 3, kk = (idx & 7) * 8;
                *(bf16x8*)&sW[rr][kk] =
                    *(const bf16x8*)&Wcb[(size_t)rr * 512 + kb + kk];
            }
        }
        __syncthreads();
        #pragma unroll
        for (int ks = 0; ks < 2; ++ks) {
            bf16x8 a = *(const bf16x8*)&sY[wave * 16 + (lane & 15)][ks * 32 + (lane >> 4) * 8];
            #pragma unroll
            for (int n = 0; n < 3; ++n) {
                bf16x8 b = *(const bf16x8*)&sW[n * 16 + (lane & 15)][ks * 32 + (lane >> 4) * 8];
                acc[n] = __builtin_amdgcn_mfma_f32_16x16x32_bf16(a, b, acc[n], 0, 0, 0);
            }
        }
        __syncthreads();
    }

    #pragma unroll
    for (int n = 0; n < 3; ++n) {
        int col = n * 16 + (lane & 15);
        int rloc = wave * 16 + (lane >> 4) * 4;
        #pragma unroll
        for (int r = 0; r < 4; ++r)
            sS[rloc + r][col] = acc[n][r];
    }
    __syncthreads();

    if (tid < 64) {
        float mx = -INFINITY;
        #pragma unroll 8
        for (int c = 0; c < CDIM; ++c) {
            float lv = sS[tid][c] + bc[c];
            sS[tid][c] = lv;
            mx = fmaxf(mx, lv);
        }
        float se = 0.f;
        #pragma unroll 8
        for (int c = 0; c < CDIM; ++c) se += expf(sS[tid][c] - mx);
        float lse = mx + logf(se);
        #pragma unroll 8
        for (int c = 0; c < CDIM; ++c)
            out[(size_t)(r0 + tid) * CDIM + c] = sS[tid][c] - lse;
    }
}

// ---------------------------------------------------------------------------
// Launcher
// ---------------------------------------------------------------------------
extern "C" void kernel_launch(void* const* d_in, const int* in_sizes, int n_in,
                              void* d_out, int out_size, void* d_ws, size_t ws_size,
                              hipStream_t stream) {
    const float* real = (const float*)d_in[0];
    const float* imag = (const float*)d_in[1];
    const int*   edges = (const int*)d_in[2];
    const float* q    = (const float*)d_in[3];
    const float* ew   = (const float*)d_in[4];
    const float* W1   = (const float*)d_in[5];
    const float* b1   = (const float*)d_in[6];
    const float* W2   = (const float*)d_in[7];
    const float* b2   = (const float*)d_in[8];
    const float* Wc   = (const float*)d_in[9];
    const float* bc   = (const float*)d_in[10];
    float* out = (float*)d_out;

    // ---- workspace carve-up ----
    char* w = (char*)d_ws;
    int*      hkey   = (int*)w;   w += (size_t)HSIZE * 4;       // 4 MB
    float*    hval   = (float*)w; w += (size_t)HSIZE * 4;       // 4 MB
    int*      cnt    = (int*)w;   w += N_NODES * 4;
    float*    rowsum = (float*)w; w += N_NODES * 4;
    float*    colsum = (float*)w; w += N_NODES * 4;
    size_t zero_bytes = (size_t)((char*)w - (char*)d_ws);
    // Non-zeroed:
    Entry* ent  = (Entry*)w; w += (size_t)N_NODES * CAP * 16;   // 16 MB
    bf16* Xr16 = (bf16*)w; w += NF * 2;
    bf16* Xi16 = (bf16*)w; w += NF * 2;
    bf16* XC   = (bf16*)w; w += NF * 4;                         // interleaved
    bf16* Z1r  = (bf16*)w; w += NF * 2;
    bf16* Z1i  = (bf16*)w; w += NF * 2;
    bf16* Z1C  = (bf16*)w; w += NF * 4;
    bf16* Z2r  = (bf16*)w; w += NF * 2;
    bf16* Z2i  = (bf16*)w; w += NF * 2;
    bf16* Y1rb = (bf16*)w; w += NF * 2;
    bf16* Y1ib = (bf16*)w; w += NF * 2;
    bf16* Y1C  = (bf16*)w; w += NF * 4;
    bf16* Y2rb = (bf16*)w; w += NF * 2;
    bf16* Y2ib = (bf16*)w; w += NF * 2;
    bf16* W1t  = (bf16*)w; w += 256 * 768 * 2;
    bf16* W2t  = (bf16*)w; w += 256 * 768 * 2;
    bf16* Wcb  = (bf16*)w; w += 48 * 512 * 2;

    hipMemsetAsync(d_ws, 0, zero_bytes, stream);

    // ---- build sparse L (hash -> ELL) ----
    hash_insert<<<(NEDGE + 255) / 256, 256, 0, stream>>>(edges, ew, hkey, hval,
                                                         rowsum, colsum);
    hash_to_ell<<<HSIZE / 256, 256, 0, stream>>>(hkey, hval, rowsum, colsum,
                                                 q, cnt, ent);

    // ---- casts ----
    cast_in2<<<NF / 256, 256, 0, stream>>>(real, imag, Xr16, Xi16, XC);
    cast_weights<<<(2 * NWT + 48 * 512 + 255) / 256, 256, 0, stream>>>(
        W1, W2, Wc, W1t, W2t, Wcb);

    dim3 gW(FDIM / 64, N_NODES / 64);   // (4, 64)

    // ---- Layer 1 ----
    spmm_k<<<N_NODES, 256, 0, stream>>>(cnt, ent, XC, nullptr,
                                        1.f, 0.f, Z1r, Z1i, Z1C);
    spmm_k<<<N_NODES, 256, 0, stream>>>(cnt, ent, Z1C, XC,
                                        2.f, -1.f, Z2r, Z2i, nullptr);
    wapply_mfma<<<gW, 256, 0, stream>>>(Xr16, Xi16, Z1r, Z1i, Z2r, Z2i,
                                        W1t, b1,
                                        Y1rb, Y1ib,
                                        Y1C);

    // ---- Layer 2 ----
    spmm_k<<<N_NODES, 256, 0, stream>>>(cnt, ent, Y1C, nullptr,
                                        1.f, 0.f, Z1r, Z1i, Z1C);
    spmm_k<<<N_NODES, 256, 0, stream>>>(cnt, ent, Z1C, Y1C,
                                        2.f, -1.f, Z2r, Z2i, nullptr);
    wapply_mfma<<<gW, 256, 0, stream>>>(Y1rb, Y1ib, Z1r, Z1i, Z2r, Z2i,
                                        W2t, b2,
                                        Y2rb, Y2ib,
                                        nullptr);

    // ---- Head ----
    head_mfma<<<64, 256, 0, stream>>>(Y2rb, Y2ib, Wcb, bc, out);
}

// Round 5
// 268.545 us; speedup vs baseline: 1.1885x; 1.1725x over previous
//
#include <hip/hip_runtime.h>
#include <cmath>

#define N_NODES 4096
#define FDIM    256
#define CDIM    40
#define NEDGE   131072
#define CAP     256                  // ELL row capacity (row nnz ~Poisson(64))
#define HBITS   20
#define HSIZE   (1 << HBITS)         // 1M hash slots, load <= 0.125
#define TWO_PI_F 6.28318530717958647692f

typedef __bf16 bf16;
typedef __bf16 bf16x2 __attribute__((ext_vector_type(2)));
typedef __bf16 bf16x4 __attribute__((ext_vector_type(4)));
typedef __bf16 bf16x8 __attribute__((ext_vector_type(8)));
typedef _Float16 f16;
typedef _Float16 f16x2 __attribute__((ext_vector_type(2)));
typedef float  f32x4  __attribute__((ext_vector_type(4)));

static constexpr size_t NF = (size_t)N_NODES * FDIM;      // 1,048,576

// Entry now carries PRE-PACKED half2 coefficient pairs:
//   ab = (lr, -li), ba = (li, lr)  so that per complex feature (xr,xi):
//   ar += dot2(ab, x)   ai += dot2(ba, x)   -- one instruction each.
struct __align__(16) Entry { unsigned ab, ba; int col, pad; };

__device__ __forceinline__ unsigned pack_h2(float a, float b) {
    f16x2 h; h[0] = (f16)a; h[1] = (f16)b;
    return __builtin_bit_cast(unsigned, h);
}
__device__ __forceinline__ f16x2 bch2(unsigned u) {
    return __builtin_bit_cast(f16x2, u);
}

// 2-way f16 dot product with f32 accumulate: d = a.x*b.x + a.y*b.y + c
__device__ __forceinline__ float fdot2(f16x2 a, f16x2 b, float c) {
#if __has_builtin(__builtin_amdgcn_fdot2)
    return __builtin_amdgcn_fdot2(a, b, c, false);
#else
    asm("v_dot2_f32_f16 %0, %1, %2, %0" : "+v"(c) : "v"(a), "v"(b));
    return c;
#endif
}

// async global->LDS, 16B per lane, dest = ldsBase + lane*16
__device__ __forceinline__ void gld_lds16(const bf16* g, bf16* s) {
    __builtin_amdgcn_global_load_lds(
        (const __attribute__((address_space(1))) void*)g,
        (__attribute__((address_space(3))) void*)s,
        16, 0, 0);
}

__device__ __forceinline__ unsigned cell_hash(unsigned cell) {
    return (cell * 2654435761u) >> (32 - HBITS);
}

// ---------------------------------------------------------------------------
// 1. Hash-insert edges (duplicate weights summed) + raw row/col degree sums.
// ---------------------------------------------------------------------------
__global__ void hash_insert(const int* __restrict__ edges,
                            const float* __restrict__ ew,
                            int* __restrict__ hkey, float* __restrict__ hval,
                            float* __restrict__ rowsum, float* __restrict__ colsum) {
    int e = blockIdx.x * blockDim.x + threadIdx.x;
    if (e >= NEDGE) return;
    int r = edges[e], c = edges[NEDGE + e];
    float wv = ew[e];
    atomicAdd(rowsum + r, wv);
    atomicAdd(colsum + c, wv);
    unsigned cell = (unsigned)r * N_NODES + c;      // < 2^24
    unsigned h = cell_hash(cell);
    for (;;) {
        int old = atomicCAS(hkey + h, 0, (int)(cell + 1));
        if (old == 0 || old == (int)(cell + 1)) { atomicAdd(hval + h, wv); break; }
        h = (h + 1) & (HSIZE - 1);
    }
}

// ---------------------------------------------------------------------------
// 2. Hash -> ELL, dinv inlined; coefficients packed to half2 pairs.
// ---------------------------------------------------------------------------
__global__ __launch_bounds__(256) void hash_to_ell(
    const int* __restrict__ hkey, const float* __restrict__ hval,
    const float* __restrict__ rowsum, const float* __restrict__ colsum,
    const float* __restrict__ qptr,
    int* __restrict__ cnt, Entry* __restrict__ ent) {
    int h = blockIdx.x * 256 + threadIdx.x;
    int k = hkey[h];
    if (k == 0) return;
    unsigned cell = (unsigned)(k - 1);
    int i = cell >> 12, j = cell & 4095;
    float a = hval[h];
    float b = 0.f;
    bool mirror = false;
    if (i == j) { b = a; mirror = true; }
    else {
        unsigned mcell = (unsigned)j * N_NODES + i;
        unsigned hh = cell_hash(mcell);
        for (;;) {
            int kk = hkey[hh];
            if (kk == (int)(mcell + 1)) { b = hval[hh]; mirror = true; break; }
            if (kk == 0) break;
            hh = (hh + 1) & (HSIZE - 1);
        }
    }
    float di = 0.5f * (rowsum[i] + colsum[i]); if (di == 0.f) di = 1.f;
    float dj = 0.5f * (rowsum[j] + colsum[j]); if (dj == 0.f) dj = 1.f;
    float an = 0.5f * (a + b) / sqrtf(di * dj);
    float s, c;
    sincosf(TWO_PI_F * qptr[0] * (a - b), &s, &c);
    float lr = -an * c;
    float li = an * s;                 // for (i,j); conjugate uses -li
    int pos = atomicAdd(cnt + i, 1);
    if (pos < CAP) {
        Entry en; en.ab = pack_h2(lr, -li); en.ba = pack_h2(li, lr);
        en.col = j; en.pad = 0;
        ent[(size_t)i * CAP + pos] = en;
    }
    if (!mirror) {   // emit conjugate cell (j,i): (lr, -li)
        int pos2 = atomicAdd(cnt + j, 1);
        if (pos2 < CAP) {
            Entry en; en.ab = pack_h2(lr, li); en.ba = pack_h2(-li, lr);
            en.col = i; en.pad = 0;
            ent[(size_t)j * CAP + pos2] = en;
        }
    }
}

// ---------------------------------------------------------------------------
// 3. Cast X -> planar bf16 (wapply input) + interleaved f16 (spmm input)
// ---------------------------------------------------------------------------
__global__ __launch_bounds__(256) void cast_in2(const float* __restrict__ Xr,
                                                const float* __restrict__ Xi,
                                                bf16* __restrict__ Xr16,
                                                bf16* __restrict__ Xi16,
                                                f16* __restrict__ XC) {
    int idx = blockIdx.x * 256 + threadIdx.x;     // n*256+f
    float vr = Xr[idx], vi = Xi[idx];
    Xr16[idx] = (bf16)vr; Xi16[idx] = (bf16)vi;
    ((unsigned*)XC)[idx] = pack_h2(vr, vi);
}

// ---------------------------------------------------------------------------
// 4. Fused weight casts.
// ---------------------------------------------------------------------------
#define NWT (256 * 768)
__global__ __launch_bounds__(256) void cast_weights(
    const float* __restrict__ W1, const float* __restrict__ W2,
    const float* __restrict__ Wc,
    bf16* __restrict__ W1t, bf16* __restrict__ W2t, bf16* __restrict__ Wcb) {
    int idx = blockIdx.x * 256 + threadIdx.x;
    if (idx < 2 * NWT) {
        const float* W = (idx < NWT) ? W1 : W2;
        bf16* Wt = (idx < NWT) ? W1t : W2t;
        int id = (idx < NWT) ? idx : idx - NWT;
        int nout = id / 768, kk = id - nout * 768;
        int o = kk >> 8, k = kk & 255;
        Wt[id] = (bf16)W[((size_t)o * 256 + k) * 256 + nout];
    } else {
        int id = idx - 2 * NWT;
        if (id < 48 * 512) {
            int row = id >> 9, k = id & 511;
            Wcb[id] = (row < CDIM) ? (bf16)Wc[row * 512 + k] : (bf16)0.f;
        }
    }
}

// ---------------------------------------------------------------------------
// 5. Sparse complex SpMM (ELL), v7: round-0 structure (one block / row,
//    4 waves, entries wave-strided, 4 gathers in flight) with the MAC core
//    switched to v_dot2_f32_f16 on f16 data + pre-packed coefficients.
//    ~13 wave-inst per entry vs ~26 before (VALU-issue bound).
// ---------------------------------------------------------------------------
__global__ __launch_bounds__(256) void spmm_k(
    const int* __restrict__ cnt, const Entry* __restrict__ ent,
    const f16* __restrict__ XC,
    const f16* __restrict__ C0C,
    float alpha, float beta,
    bf16* __restrict__ Zr, bf16* __restrict__ Zi, f16* __restrict__ ZC)
{
    __shared__ f32x4 redR[3][64];
    __shared__ f32x4 redI[3][64];

    const int wave = threadIdx.x >> 6, lane = threadIdx.x & 63;
    const int row = blockIdx.x;
    int n1 = cnt[row]; if (n1 > CAP) n1 = CAP;
    const Entry* erow = ent + (size_t)row * CAP;

    float ar[4] = {}, ai[4] = {};
    int e = wave;
    // 4 independent XC gathers in flight (entries e, e+4, e+8, e+12)
    for (; e + 12 < n1; e += 16) {
        Entry e0 = erow[e];
        Entry e1 = erow[e + 4];
        Entry e2 = erow[e + 8];
        Entry e3 = erow[e + 12];
        uint4 x0 = *(const uint4*)&XC[(size_t)(e0.col & 4095) * 512 + lane * 8];
        uint4 x1 = *(const uint4*)&XC[(size_t)(e1.col & 4095) * 512 + lane * 8];
        uint4 x2 = *(const uint4*)&XC[(size_t)(e2.col & 4095) * 512 + lane * 8];
        uint4 x3 = *(const uint4*)&XC[(size_t)(e3.col & 4095) * 512 + lane * 8];
        {
            f16x2 ab = bch2(e0.ab), ba = bch2(e0.ba);
            ar[0] = fdot2(ab, bch2(x0.x), ar[0]); ai[0] = fdot2(ba, bch2(x0.x), ai[0]);
            ar[1] = fdot2(ab, bch2(x0.y), ar[1]); ai[1] = fdot2(ba, bch2(x0.y), ai[1]);
            ar[2] = fdot2(ab, bch2(x0.z), ar[2]); ai[2] = fdot2(ba, bch2(x0.z), ai[2]);
            ar[3] = fdot2(ab, bch2(x0.w), ar[3]); ai[3] = fdot2(ba, bch2(x0.w), ai[3]);
        }
        {
            f16x2 ab = bch2(e1.ab), ba = bch2(e1.ba);
            ar[0] = fdot2(ab, bch2(x1.x), ar[0]); ai[0] = fdot2(ba, bch2(x1.x), ai[0]);
            ar[1] = fdot2(ab, bch2(x1.y), ar[1]); ai[1] = fdot2(ba, bch2(x1.y), ai[1]);
            ar[2] = fdot2(ab, bch2(x1.z), ar[2]); ai[2] = fdot2(ba, bch2(x1.z), ai[2]);
            ar[3] = fdot2(ab, bch2(x1.w), ar[3]); ai[3] = fdot2(ba, bch2(x1.w), ai[3]);
        }
        {
            f16x2 ab = bch2(e2.ab), ba = bch2(e2.ba);
            ar[0] = fdot2(ab, bch2(x2.x), ar[0]); ai[0] = fdot2(ba, bch2(x2.x), ai[0]);
            ar[1] = fdot2(ab, bch2(x2.y), ar[1]); ai[1] = fdot2(ba, bch2(x2.y), ai[1]);
            ar[2] = fdot2(ab, bch2(x2.z), ar[2]); ai[2] = fdot2(ba, bch2(x2.z), ai[2]);
            ar[3] = fdot2(ab, bch2(x2.w), ar[3]); ai[3] = fdot2(ba, bch2(x2.w), ai[3]);
        }
        {
            f16x2 ab = bch2(e3.ab), ba = bch2(e3.ba);
            ar[0] = fdot2(ab, bch2(x3.x), ar[0]); ai[0] = fdot2(ba, bch2(x3.x), ai[0]);
            ar[1] = fdot2(ab, bch2(x3.y), ar[1]); ai[1] = fdot2(ba, bch2(x3.y), ai[1]);
            ar[2] = fdot2(ab, bch2(x3.z), ar[2]); ai[2] = fdot2(ba, bch2(x3.z), ai[2]);
            ar[3] = fdot2(ab, bch2(x3.w), ar[3]); ai[3] = fdot2(ba, bch2(x3.w), ai[3]);
        }
    }
    for (; e < n1; e += 4) {
        Entry e0 = erow[e];
        uint4 x0 = *(const uint4*)&XC[(size_t)(e0.col & 4095) * 512 + lane * 8];
        f16x2 ab = bch2(e0.ab), ba = bch2(e0.ba);
        ar[0] = fdot2(ab, bch2(x0.x), ar[0]); ai[0] = fdot2(ba, bch2(x0.x), ai[0]);
        ar[1] = fdot2(ab, bch2(x0.y), ar[1]); ai[1] = fdot2(ba, bch2(x0.y), ai[1]);
        ar[2] = fdot2(ab, bch2(x0.z), ar[2]); ai[2] = fdot2(ba, bch2(x0.z), ai[2]);
        ar[3] = fdot2(ab, bch2(x0.w), ar[3]); ai[3] = fdot2(ba, bch2(x0.w), ai[3]);
    }

    if (wave != 0) {
        f32x4 r, i;
        #pragma unroll
        for (int c = 0; c < 4; ++c) { r[c] = ar[c]; i[c] = ai[c]; }
        redR[wave - 1][lane] = r;
        redI[wave - 1][lane] = i;
    }
    __syncthreads();
    if (wave != 0) return;

    #pragma unroll
    for (int w = 0; w < 3; ++w) {
        f32x4 r = redR[w][lane], i = redI[w][lane];
        #pragma unroll
        for (int c = 0; c < 4; ++c) { ar[c] += r[c]; ai[c] += i[c]; }
    }

    float vr[4], vi[4];
    if (beta != 0.f) {
        uint4 c0 = *(const uint4*)&C0C[(size_t)row * 512 + lane * 8];
        f16x2 h0 = bch2(c0.x), h1 = bch2(c0.y), h2 = bch2(c0.z), h3 = bch2(c0.w);
        vr[0] = alpha * ar[0] + beta * (float)h0[0];
        vi[0] = alpha * ai[0] + beta * (float)h0[1];
        vr[1] = alpha * ar[1] + beta * (float)h1[0];
        vi[1] = alpha * ai[1] + beta * (float)h1[1];
        vr[2] = alpha * ar[2] + beta * (float)h2[0];
        vi[2] = alpha * ai[2] + beta * (float)h2[1];
        vr[3] = alpha * ar[3] + beta * (float)h3[0];
        vi[3] = alpha * ai[3] + beta * (float)h3[1];
    } else {
        #pragma unroll
        for (int c = 0; c < 4; ++c) { vr[c] = alpha * ar[c]; vi[c] = alpha * ai[c]; }
    }
    size_t base = (size_t)row * FDIM + lane * 4;
    bf16x4 pr, pi;
    #pragma unroll
    for (int c = 0; c < 4; ++c) { pr[c] = (bf16)vr[c]; pi[c] = (bf16)vi[c]; }
    *(bf16x4*)&Zr[base] = pr;
    *(bf16x4*)&Zi[base] = pi;
    if (ZC) {
        uint4 o;
        o.x = pack_h2(vr[0], vi[0]);
        o.y = pack_h2(vr[1], vi[1]);
        o.z = pack_h2(vr[2], vi[2]);
        o.w = pack_h2(vr[3], vi[3]);
        *(uint4*)&ZC[(size_t)row * 512 + lane * 8] = o;
    }
}

// ---------------------------------------------------------------------------
// 6. wapply via MFMA (round-0 core; dead f32 outputs removed; OC now f16).
// ---------------------------------------------------------------------------
__global__ __launch_bounds__(256) void wapply_mfma(
    const bf16* __restrict__ Z0r, const bf16* __restrict__ Z0i,
    const bf16* __restrict__ Z1r, const bf16* __restrict__ Z1i,
    const bf16* __restrict__ Z2r, const bf16* __restrict__ Z2i,
    const bf16* __restrict__ Wt,      // [256][768]
    const float* __restrict__ bias,   // [256]
    bf16* __restrict__ O16r_r, bf16* __restrict__ O16r_i,
    f16* __restrict__ OC)
{
    __shared__ __align__(16) bf16 sZr[64 * 32];
    __shared__ __align__(16) bf16 sZi[64 * 32];
    __shared__ __align__(16) bf16 sW [64 * 32];

    const int tid  = threadIdx.x;
    const int wave = tid >> 6;
    const int lane = tid & 63;
    const int rowBase = blockIdx.y * 64;
    const int colBase = blockIdx.x * 64;

    const int srow = lane >> 2;
    const int skc  = (lane & 3) * 8;

    f32x4 accSr[2][2] = {}, accSi[2][2] = {};
    const int wm = wave & 1, wn = wave >> 1;
    const int fr = lane & 15;
    const int fk = (lane >> 4) * 8;

    for (int kb = 0; kb < 3 * FDIM; kb += 32) {
        int order = kb >> 8;
        int kloc  = kb & 255;
        if (wave == 0 || wave == 1) {
            const bf16* z;
            if (wave == 0) z = (order == 0) ? Z0r : (order == 1) ? Z1r : Z2r;
            else           z = (order == 0) ? Z0i : (order == 1) ? Z1i : Z2i;
            bf16* s = (wave == 0) ? sZr : sZi;
            const bf16* g = z + (size_t)(rowBase + srow) * FDIM + kloc + skc;
            #pragma unroll
            for (int t = 0; t < 4; ++t)
                gld_lds16(g + (size_t)t * 16 * FDIM, s + t * 512);
        } else if (wave == 2) {
            const bf16* g = Wt + (size_t)(colBase + srow) * 768 + kb + skc;
            #pragma unroll
            for (int t = 0; t < 4; ++t)
                gld_lds16(g + (size_t)t * 16 * 768, sW + t * 512);
        }
        __syncthreads();

        bf16x8 zr[2], zi[2], wv[2];
        #pragma unroll
        for (int m = 0; m < 2; ++m) {
            int r = wm * 32 + m * 16 + fr;
            zr[m] = *(const bf16x8*)&sZr[r * 32 + fk];
            zi[m] = *(const bf16x8*)&sZi[r * 32 + fk];
        }
        #pragma unroll
        for (int n = 0; n < 2; ++n) {
            int c = wn * 32 + n * 16 + fr;
            wv[n] = *(const bf16x8*)&sW[c * 32 + fk];
        }
        #pragma unroll
        for (int m = 0; m < 2; ++m)
            #pragma unroll
            for (int n = 0; n < 2; ++n) {
                accSr[m][n] = __builtin_amdgcn_mfma_f32_16x16x32_bf16(zr[m], wv[n], accSr[m][n], 0, 0, 0);
                accSi[m][n] = __builtin_amdgcn_mfma_f32_16x16x32_bf16(zi[m], wv[n], accSi[m][n], 0, 0, 0);
            }
        __syncthreads();
    }

    #pragma unroll
    for (int m = 0; m < 2; ++m)
        #pragma unroll
        for (int n = 0; n < 2; ++n) {
            int row0 = rowBase + wm * 32 + m * 16 + (lane >> 4) * 4;
            int col  = colBase + wn * 32 + n * 16 + (lane & 15);
            float bv = bias[col];
            #pragma unroll
            for (int r = 0; r < 4; ++r) {
                float vr = bv - accSi[m][n][r];
                float vi = bv + accSr[m][n][r];
                int row = row0 + r;
                size_t idx = (size_t)row * FDIM + col;
                if (O16r_r) {
                    O16r_r[idx] = (bf16)vr; O16r_i[idx] = (bf16)vi;
                }
                if (OC) {
                    ((unsigned*)OC)[idx] = pack_h2(vr, vi);
                }
            }
        }
}

// ---------------------------------------------------------------------------
// 7. Head via MFMA + fused log_softmax (unchanged).
// ---------------------------------------------------------------------------
__global__ __launch_bounds__(256) void head_mfma(
    const bf16* __restrict__ Yrb,
    const bf16* __restrict__ Yib,
    const bf16* __restrict__ Wcb,
    const float* __restrict__ bc,
    float* __restrict__ out)          // [4096][40]
{
    __shared__ __align__(16) bf16 sY[64][72];
    __shared__ __align__(16) bf16 sW[48][72];
    __shared__ float sS[64][52];

    const int tid  = threadIdx.x;
    const int wave = tid >> 6;
    const int lane = tid & 63;
    const int r0 = blockIdx.x * 64;

    f32x4 acc[3] = {};

    for (int kb = 0; kb < 512; kb += 64) {
        const bf16* src = (kb < 256) ? Yrb : Yib;
        const int koff = kb & 255;
        #pragma unroll
        for (int e = 0; e < 2; ++e) {
            int idx = tid + e * 256;             // 0..511
            int rr = idx >> 3, kk = (idx & 7) * 8;
            *(bf16x8*)&sY[rr][kk] =
                *(const bf16x8*)&src[(size_t)(r0 + rr) * FDIM + koff + kk];
        }
        #pragma unroll
        for (int e = 0; e < 2; ++e) {
            int idx = tid + e * 256;             // need 0..383
            if (idx < 384) {
                int rr = idx >> 3, kk = (idx & 7) * 8;
                *(bf16x8*)&sW[rr][kk] =
                    *(const bf16x8*)&Wcb[(size_t)rr * 512 + kb + kk];
            }
        }
        __syncthreads();
        #pragma unroll
        for (int ks = 0; ks < 2; ++ks) {
            bf16x8 a = *(const bf16x8*)&sY[wave * 16 + (lane & 15)][ks * 32 + (lane >> 4) * 8];
            #pragma unroll
            for (int n = 0; n < 3; ++n) {
                bf16x8 b = *(const bf16x8*)&sW[n * 16 + (lane & 15)][ks * 32 + (lane >> 4) * 8];
                acc[n] = __builtin_amdgcn_mfma_f32_16x16x32_bf16(a, b, acc[n], 0, 0, 0);
            }
        }
        __syncthreads();
    }

    #pragma unroll
    for (int n = 0; n < 3; ++n) {
        int col = n * 16 + (lane & 15);
        int rloc = wave * 16 + (lane >> 4) * 4;
        #pragma unroll
        for (int r = 0; r < 4; ++r)
            sS[rloc + r][col] = acc[n][r];
    }
    __syncthreads();

    if (tid < 64) {
        float mx = -INFINITY;
        #pragma unroll 8
        for (int c = 0; c < CDIM; ++c) {
            float lv = sS[tid][c] + bc[c];
            sS[tid][c] = lv;
            mx = fmaxf(mx, lv);
        }
        float se = 0.f;
        #pragma unroll 8
        for (int c = 0; c < CDIM; ++c) se += expf(sS[tid][c] - mx);
        float lse = mx + logf(se);
        #pragma unroll 8
        for (int c = 0; c < CDIM; ++c)
            out[(size_t)(r0 + tid) * CDIM + c] = sS[tid][c] - lse;
    }
}

// ---------------------------------------------------------------------------
// Launcher
// ---------------------------------------------------------------------------
extern "C" void kernel_launch(void* const* d_in, const int* in_sizes, int n_in,
                              void* d_out, int out_size, void* d_ws, size_t ws_size,
                              hipStream_t stream) {
    const float* real = (const float*)d_in[0];
    const float* imag = (const float*)d_in[1];
    const int*   edges = (const int*)d_in[2];
    const float* q    = (const float*)d_in[3];
    const float* ew   = (const float*)d_in[4];
    const float* W1   = (const float*)d_in[5];
    const float* b1   = (const float*)d_in[6];
    const float* W2   = (const float*)d_in[7];
    const float* b2   = (const float*)d_in[8];
    const float* Wc   = (const float*)d_in[9];
    const float* bc   = (const float*)d_in[10];
    float* out = (float*)d_out;

    // ---- workspace carve-up ----
    char* w = (char*)d_ws;
    int*      hkey   = (int*)w;   w += (size_t)HSIZE * 4;       // 4 MB
    float*    hval   = (float*)w; w += (size_t)HSIZE * 4;       // 4 MB
    int*      cnt    = (int*)w;   w += N_NODES * 4;
    float*    rowsum = (float*)w; w += N_NODES * 4;
    float*    colsum = (float*)w; w += N_NODES * 4;
    size_t zero_bytes = (size_t)((char*)w - (char*)d_ws);
    // Non-zeroed:
    Entry* ent  = (Entry*)w; w += (size_t)N_NODES * CAP * 16;   // 16 MB
    bf16* Xr16 = (bf16*)w; w += NF * 2;
    bf16* Xi16 = (bf16*)w; w += NF * 2;
    f16*  XC   = (f16*)w;  w += NF * 4;                         // interleaved f16
    bf16* Z1r  = (bf16*)w; w += NF * 2;
    bf16* Z1i  = (bf16*)w; w += NF * 2;
    f16*  Z1C  = (f16*)w;  w += NF * 4;
    bf16* Z2r  = (bf16*)w; w += NF * 2;
    bf16* Z2i  = (bf16*)w; w += NF * 2;
    bf16* Y1rb = (bf16*)w; w += NF * 2;
    bf16* Y1ib = (bf16*)w; w += NF * 2;
    f16*  Y1C  = (f16*)w;  w += NF * 4;
    bf16* Y2rb = (bf16*)w; w += NF * 2;
    bf16* Y2ib = (bf16*)w; w += NF * 2;
    bf16* W1t  = (bf16*)w; w += 256 * 768 * 2;
    bf16* W2t  = (bf16*)w; w += 256 * 768 * 2;
    bf16* Wcb  = (bf16*)w; w += 48 * 512 * 2;

    hipMemsetAsync(d_ws, 0, zero_bytes, stream);

    // ---- build sparse L (hash -> ELL) ----
    hash_insert<<<(NEDGE + 255) / 256, 256, 0, stream>>>(edges, ew, hkey, hval,
                                                         rowsum, colsum);
    hash_to_ell<<<HSIZE / 256, 256, 0, stream>>>(hkey, hval, rowsum, colsum,
                                                 q, cnt, ent);

    // ---- casts ----
    cast_in2<<<NF / 256, 256, 0, stream>>>(real, imag, Xr16, Xi16, XC);
    cast_weights<<<(2 * NWT + 48 * 512 + 255) / 256, 256, 0, stream>>>(
        W1, W2, Wc, W1t, W2t, Wcb);

    dim3 gW(FDIM / 64, N_NODES / 64);   // (4, 64)

    // ---- Layer 1 ----
    spmm_k<<<N_NODES, 256, 0, stream>>>(cnt, ent, XC, nullptr,
                                        1.f, 0.f, Z1r, Z1i, Z1C);
    spmm_k<<<N_NODES, 256, 0, stream>>>(cnt, ent, Z1C, XC,
                                        2.f, -1.f, Z2r, Z2i, nullptr);
    wapply_mfma<<<gW, 256, 0, stream>>>(Xr16, Xi16, Z1r, Z1i, Z2r, Z2i,
                                        W1t, b1,
                                        Y1rb, Y1ib,
                                        Y1C);

    // ---- Layer 2 ----
    spmm_k<<<N_NODES, 256, 0, stream>>>(cnt, ent, Y1C, nullptr,
                                        1.f, 0.f, Z1r, Z1i, Z1C);
    spmm_k<<<N_NODES, 256, 0, stream>>>(cnt, ent, Z1C, Y1C,
                                        2.f, -1.f, Z2r, Z2i, nullptr);
    wapply_mfma<<<gW, 256, 0, stream>>>(Y1rb, Y1ib, Z1r, Z1i, Z2r, Z2i,
                                        W2t, b2,
                                        Y2rb, Y2ib,
                                        nullptr);

    // ---- Head ----
    head_mfma<<<64, 256, 0, stream>>>(Y2rb, Y2ib, Wcb, bc, out);
}